// Round 1
// baseline (910.296 us; speedup 1.0000x reference)
//
#include <hip/hip_runtime.h>
#include <hip/hip_bf16.h>
#include <math.h>

// ---------------------------------------------------------------------------
// GATv2 x2 + MLP head, fp32 throughout (correctness-first round).
//   xs = x@Wl + bl ; xd = x@Wr + br          (tiled SGEMM, VALU)
//   per-edge: e = att . leaky_relu(xs[src]+xd[dst]); per-dst softmax; out = sum alpha*xs[src]
//   edge phase: CSR-by-dst + one wave per (node,head), online softmax, no atomics
// ---------------------------------------------------------------------------

#define BM 64
#define BN 64
#define BK 16

__global__ __launch_bounds__(256) void sgemm_bias(
    const float* __restrict__ A, const float* __restrict__ W,
    const float* __restrict__ bias, float* __restrict__ C,
    int M, int N, int K)
{
    __shared__ float As[BK][BM];
    __shared__ float Bs[BK][BN];
    int tid = threadIdx.x;
    int col0 = blockIdx.x * BN;
    int row0 = blockIdx.y * BM;

    // A tile load: 64 rows x 16 cols, one float4 per thread
    int arow = tid >> 2;
    int acol = (tid & 3) << 2;
    // B tile load: 16 rows x 64 cols, one float4 per thread
    int brow = tid >> 4;
    int bcol = (tid & 15) << 2;

    int ty = tid >> 4;   // 0..15 -> 4 rows each
    int tx = tid & 15;   // 0..15 -> 4 cols each

    float acc[4][4] = {};

    for (int k0 = 0; k0 < K; k0 += BK) {
        float4 av = make_float4(0.f, 0.f, 0.f, 0.f);
        int gr = row0 + arow;
        if (gr < M) av = *(const float4*)&A[(size_t)gr * K + k0 + acol];
        As[acol + 0][arow] = av.x;
        As[acol + 1][arow] = av.y;
        As[acol + 2][arow] = av.z;
        As[acol + 3][arow] = av.w;
        float4 bv = *(const float4*)&W[(size_t)(k0 + brow) * N + col0 + bcol];
        *(float4*)&Bs[brow][bcol] = bv;
        __syncthreads();
#pragma unroll
        for (int k = 0; k < BK; ++k) {
            float a[4], b[4];
#pragma unroll
            for (int i = 0; i < 4; ++i) a[i] = As[k][ty * 4 + i];
#pragma unroll
            for (int j = 0; j < 4; ++j) b[j] = Bs[k][tx * 4 + j];
#pragma unroll
            for (int i = 0; i < 4; ++i)
#pragma unroll
                for (int j = 0; j < 4; ++j)
                    acc[i][j] += a[i] * b[j];
        }
        __syncthreads();
    }

#pragma unroll
    for (int i = 0; i < 4; ++i) {
        int r = row0 + ty * 4 + i;
        if (r < M) {
            int c = col0 + tx * 4;
            float4 o;
            o.x = acc[i][0] + bias[c + 0];
            o.y = acc[i][1] + bias[c + 1];
            o.z = acc[i][2] + bias[c + 2];
            o.w = acc[i][3] + bias[c + 3];
            *(float4*)&C[(size_t)r * N + c] = o;
        }
    }
}

// ----------------------------- CSR construction -----------------------------

__global__ void count_edges(const int* __restrict__ dst, int* __restrict__ counts, int E)
{
    int i = blockIdx.x * blockDim.x + threadIdx.x;
    if (i < E) atomicAdd(&counts[dst[i]], 1);
}

__global__ __launch_bounds__(1024) void scan_kernel(
    const int* __restrict__ counts, int* __restrict__ row_ptr,
    int* __restrict__ cursor, int n)
{
    __shared__ int wsum[16];
    __shared__ int stot;
    int tid = threadIdx.x;
    int lane = tid & 63, wid = tid >> 6;
    int offset = 0;
    for (int base = 0; base < n; base += 1024) {
        int idx = base + tid;
        int v = (idx < n) ? counts[idx] : 0;
        int x = v;
#pragma unroll
        for (int off = 1; off < 64; off <<= 1) {
            int y = __shfl_up(x, off);
            if (lane >= off) x += y;
        }
        if (lane == 63) wsum[wid] = x;
        __syncthreads();
        if (tid == 0) {
            int run = 0;
#pragma unroll
            for (int i = 0; i < 16; ++i) { int t = wsum[i]; wsum[i] = run; run += t; }
            stot = run;
        }
        __syncthreads();
        int excl = offset + wsum[wid] + x - v;
        if (idx < n) { row_ptr[idx] = excl; cursor[idx] = excl; }
        offset += stot;
        __syncthreads();   // protect wsum/stot before next chunk overwrites
    }
    if (tid == 0) row_ptr[n] = offset;
}

__global__ void scatter_edges(const int* __restrict__ src, const int* __restrict__ dst,
                              int* __restrict__ cursor, int* __restrict__ csr_src, int E)
{
    int i = blockIdx.x * blockDim.x + threadIdx.x;
    if (i < E) {
        int pos = atomicAdd(&cursor[dst[i]], 1);
        csr_src[pos] = src[i];
    }
}

// ------------------------- per-(node,head) aggregation -----------------------
// One wave per (node, head). lane handles dims {2*lane, 2*lane+1} of 128.
// Online softmax over incoming edges (self-loop handled as extra iteration).

__global__ __launch_bounds__(256) void gat_agg(
    const float* __restrict__ xs, const float* __restrict__ xd,
    const float* __restrict__ att, const float* __restrict__ bias,
    const int* __restrict__ row_ptr, const int* __restrict__ csr_src,
    float* __restrict__ out, int n)
{
    int gw = blockIdx.x * 4 + (threadIdx.x >> 6);
    int node = gw >> 1;
    int head = gw & 1;
    if (node >= n) return;
    int lane = threadIdx.x & 63;
    int base = head * 128 + lane * 2;

    float2 xdv = *(const float2*)&xd[(size_t)node * 256 + base];
    float2 atv = *(const float2*)&att[base];

    float m = -INFINITY, l = 0.f;
    float2 acc = make_float2(0.f, 0.f);

    int s = row_ptr[node], e = row_ptr[node + 1];
    for (int i = s - 1; i < e; ++i) {          // i==s-1 -> self loop
        int srcn = (i < s) ? node : csr_src[i];
        float2 xv = *(const float2*)&xs[(size_t)srcn * 256 + base];
        float v0 = xv.x + xdv.x; v0 = v0 > 0.f ? v0 : 0.2f * v0;
        float v1 = xv.y + xdv.y; v1 = v1 > 0.f ? v1 : 0.2f * v1;
        float p = v0 * atv.x + v1 * atv.y;
#pragma unroll
        for (int off = 32; off; off >>= 1) p += __shfl_xor(p, off);
        float mn = fmaxf(m, p);
        float sc = __expf(m - mn);     // exp(-inf)=0 on first iteration
        float w  = __expf(p - mn);
        l = l * sc + w;
        acc.x = acc.x * sc + w * xv.x;
        acc.y = acc.y * sc + w * xv.y;
        m = mn;
    }
    float inv = 1.f / (l + 1e-16f);
    float o0 = fmaxf(acc.x * inv + bias[base + 0], 0.f);   // + bias, then ReLU
    float o1 = fmaxf(acc.y * inv + bias[base + 1], 0.f);
    *(float2*)&out[(size_t)node * 256 + base] = make_float2(o0, o1);
}

// --------------------------- final GEMV + sigmoid ---------------------------

__global__ __launch_bounds__(256) void mlp2_kernel(
    const float* __restrict__ t, const float* __restrict__ W4,
    const float* __restrict__ b4, float* __restrict__ out, int n)
{
    int w = (int)((blockIdx.x * blockDim.x + threadIdx.x) >> 6);
    int lane = threadIdx.x & 63;
    if (w >= n) return;
    float2 tv = *(const float2*)&t[(size_t)w * 128 + lane * 2];
    float2 wv = *(const float2*)&W4[lane * 2];
    float p = tv.x * wv.x + tv.y * wv.y;
#pragma unroll
    for (int off = 32; off; off >>= 1) p += __shfl_xor(p, off);
    if (lane == 0) out[w] = 1.f / (1.f + __expf(-(p + b4[0])));
}

// ---------------------------------------------------------------------------

extern "C" void kernel_launch(void* const* d_in, const int* in_sizes, int n_in,
                              void* d_out, int out_size, void* d_ws, size_t ws_size,
                              hipStream_t stream)
{
    const float* x     = (const float*)d_in[0];
    const int*   ei    = (const int*)d_in[1];
    const float* Wl1   = (const float*)d_in[2];
    const float* bl1   = (const float*)d_in[3];
    const float* Wr1   = (const float*)d_in[4];
    const float* br1   = (const float*)d_in[5];
    const float* att1  = (const float*)d_in[6];
    const float* bias1 = (const float*)d_in[7];
    const float* Wl2   = (const float*)d_in[8];
    const float* bl2   = (const float*)d_in[9];
    const float* Wr2   = (const float*)d_in[10];
    const float* br2   = (const float*)d_in[11];
    const float* att2  = (const float*)d_in[12];
    const float* bias2 = (const float*)d_in[13];
    const float* W3    = (const float*)d_in[14];
    const float* b3    = (const float*)d_in[15];
    const float* W4    = (const float*)d_in[16];
    const float* b4    = (const float*)d_in[17];

    const int N = in_sizes[0] / 128;     // 50000
    const int E = in_sizes[1] / 2;       // 600000
    const int* src = ei;
    const int* dst = ei + E;

    char* ws = (char*)d_ws;
    float* xs      = (float*)(ws + 0);            // [N,256] 51.2 MB
    float* xd      = (float*)(ws + 51200000);     // [N,256]
    float* h       = (float*)(ws + 102400000);    // [N,256]
    int*   row_ptr = (int*)(ws + 153600000);      // N+1
    int*   counts  = (int*)(ws + 153800192);      // N
    int*   cursor  = (int*)(ws + 154000384);      // N
    int*   csr_src = (int*)(ws + 154200576);      // E

    // ---- CSR build (self-loops handled implicitly in gat_agg) ----
    hipMemsetAsync(counts, 0, N * sizeof(int), stream);
    count_edges<<<(E + 255) / 256, 256, 0, stream>>>(dst, counts, E);
    scan_kernel<<<1, 1024, 0, stream>>>(counts, row_ptr, cursor, N);
    scatter_edges<<<(E + 255) / 256, 256, 0, stream>>>(src, dst, cursor, csr_src, E);

    dim3 gN(256 / BN, (N + BM - 1) / BM);
    int aggBlocks = (N * 2 + 3) / 4;

    // ---- layer 1 ----
    sgemm_bias<<<gN, 256, 0, stream>>>(x, Wl1, bl1, xs, N, 256, 128);
    sgemm_bias<<<gN, 256, 0, stream>>>(x, Wr1, br1, xd, N, 256, 128);
    gat_agg<<<aggBlocks, 256, 0, stream>>>(xs, xd, att1, bias1, row_ptr, csr_src, h, N);

    // ---- layer 2 ----
    sgemm_bias<<<gN, 256, 0, stream>>>(h, Wl2, bl2, xs, N, 256, 256);
    sgemm_bias<<<gN, 256, 0, stream>>>(h, Wr2, br2, xd, N, 256, 256);
    gat_agg<<<aggBlocks, 256, 0, stream>>>(xs, xd, att2, bias2, row_ptr, csr_src, h, N);

    // ---- post MLP ----
    dim3 g3(128 / BN, (N + BM - 1) / BM);
    sgemm_bias<<<g3, 256, 0, stream>>>(h, W3, b3, xs, N, 128, 256);
    mlp2_kernel<<<(N * 64 + 255) / 256, 256, 0, stream>>>(xs, W4, b4, (float*)d_out, N);
}

// Round 5
// 700.863 us; speedup vs baseline: 1.2988x; 1.2988x over previous
//
#include <hip/hip_runtime.h>
#include <hip/hip_bf16.h>
#include <math.h>

// ---------------------------------------------------------------------------
// GATv2 x2 + fused MLP head, fp32.
//  R2: wave-per-node gat_agg (both heads), 128x128 8x8 SGEMM (b128 LDS reads),
//      post-MLP folded into W34 = W3@W4 and fused into layer-2 aggregation.
//  (3rd resubmit: rounds 2-4 all hit GPUAcquisitionTimeout, no data)
// ---------------------------------------------------------------------------

#define BM 128
#define BN 128
#define BK 16

__global__ __launch_bounds__(256) void sgemm_bias(
    const float* __restrict__ A, const float* __restrict__ W,
    const float* __restrict__ bias, float* __restrict__ C,
    int M, int N, int K)
{
    __shared__ float As[BK][BM];
    __shared__ float Bs[BK][BN];
    int tid = threadIdx.x;
    int col0 = blockIdx.x * BN;
    int row0 = blockIdx.y * BM;

    int arow = tid >> 2;            // 0..63
    int acol = (tid & 3) << 2;      // 0,4,8,12
    int brow = tid >> 4;            // 0..15
    int bcol = (tid & 15) << 3;     // 0..120 step 8

    int ty = tid >> 4;              // 0..15, rows ty*8..+7
    int tx = tid & 15;              // cols tx*8..+7

    float acc[8][8] = {};

    for (int k0 = 0; k0 < K; k0 += BK) {
#pragma unroll
        for (int h = 0; h < 2; ++h) {
            int gr = row0 + arow + h * 64;
            float4 av = make_float4(0.f, 0.f, 0.f, 0.f);
            if (gr < M) av = *(const float4*)&A[(size_t)gr * K + k0 + acol];
            As[acol + 0][arow + h * 64] = av.x;
            As[acol + 1][arow + h * 64] = av.y;
            As[acol + 2][arow + h * 64] = av.z;
            As[acol + 3][arow + h * 64] = av.w;
        }
        *(float4*)&Bs[brow][bcol]     = *(const float4*)&W[(size_t)(k0 + brow) * N + col0 + bcol];
        *(float4*)&Bs[brow][bcol + 4] = *(const float4*)&W[(size_t)(k0 + brow) * N + col0 + bcol + 4];
        __syncthreads();
#pragma unroll
        for (int k = 0; k < BK; ++k) {
            float a[8], b[8];
            *(float4*)&a[0] = *(float4*)&As[k][ty * 8];
            *(float4*)&a[4] = *(float4*)&As[k][ty * 8 + 4];
            *(float4*)&b[0] = *(float4*)&Bs[k][tx * 8];
            *(float4*)&b[4] = *(float4*)&Bs[k][tx * 8 + 4];
#pragma unroll
            for (int i = 0; i < 8; ++i)
#pragma unroll
                for (int j = 0; j < 8; ++j)
                    acc[i][j] += a[i] * b[j];
        }
        __syncthreads();
    }

#pragma unroll
    for (int i = 0; i < 8; ++i) {
        int r = row0 + ty * 8 + i;
        if (r < M) {
            int c = col0 + tx * 8;
            float4 o0, o1;
            o0.x = acc[i][0] + bias[c + 0];
            o0.y = acc[i][1] + bias[c + 1];
            o0.z = acc[i][2] + bias[c + 2];
            o0.w = acc[i][3] + bias[c + 3];
            o1.x = acc[i][4] + bias[c + 4];
            o1.y = acc[i][5] + bias[c + 5];
            o1.z = acc[i][6] + bias[c + 6];
            o1.w = acc[i][7] + bias[c + 7];
            *(float4*)&C[(size_t)r * N + c]     = o0;
            *(float4*)&C[(size_t)r * N + c + 4] = o1;
        }
    }
}

// ----------------------------- CSR construction -----------------------------

__global__ void count_edges(const int* __restrict__ dst, int* __restrict__ counts, int E)
{
    int i = blockIdx.x * blockDim.x + threadIdx.x;
    if (i < E) atomicAdd(&counts[dst[i]], 1);
}

__global__ __launch_bounds__(1024) void scan_kernel(
    const int* __restrict__ counts, int* __restrict__ row_ptr,
    int* __restrict__ cursor, int n)
{
    __shared__ int wsum[16];
    __shared__ int stot;
    int tid = threadIdx.x;
    int lane = tid & 63, wid = tid >> 6;
    int offset = 0;
    for (int base = 0; base < n; base += 1024) {
        int idx = base + tid;
        int v = (idx < n) ? counts[idx] : 0;
        int x = v;
#pragma unroll
        for (int off = 1; off < 64; off <<= 1) {
            int y = __shfl_up(x, off);
            if (lane >= off) x += y;
        }
        if (lane == 63) wsum[wid] = x;
        __syncthreads();
        if (tid == 0) {
            int run = 0;
#pragma unroll
            for (int i = 0; i < 16; ++i) { int t = wsum[i]; wsum[i] = run; run += t; }
            stot = run;
        }
        __syncthreads();
        int excl = offset + wsum[wid] + x - v;
        if (idx < n) { row_ptr[idx] = excl; cursor[idx] = excl; }
        offset += stot;
        __syncthreads();
    }
    if (tid == 0) row_ptr[n] = offset;
}

__global__ void scatter_edges(const int* __restrict__ src, const int* __restrict__ dst,
                              int* __restrict__ cursor, int* __restrict__ csr_src, int E)
{
    int i = blockIdx.x * blockDim.x + threadIdx.x;
    if (i < E) {
        int pos = atomicAdd(&cursor[dst[i]], 1);
        csr_src[pos] = src[i];
    }
}

// ------------------------- W34 = W3 @ W4 fold --------------------------------
// w34[0..255] = sum_j W3[i,j]*W4[j]; w34[256] = b3 . W4 + b4
__global__ __launch_bounds__(256) void w34_kernel(
    const float* __restrict__ W3, const float* __restrict__ b3,
    const float* __restrict__ W4, const float* __restrict__ b4,
    float* __restrict__ w34)
{
    int wid = blockIdx.x * 4 + (threadIdx.x >> 6);   // 0..259
    int lane = threadIdx.x & 63;
    if (wid > 256) return;
    const float* row = (wid < 256) ? &W3[(size_t)wid * 128] : b3;
    float p = row[lane] * W4[lane] + row[lane + 64] * W4[lane + 64];
#pragma unroll
    for (int off = 32; off; off >>= 1) p += __shfl_xor(p, off);
    if (lane == 0) w34[wid] = (wid < 256) ? p : (p + b4[0]);
}

// ------------------------- per-node aggregation ------------------------------
// One wave per node, both heads: lane L owns dims 4L..4L+3 of 256.
// Lanes 0..31 = head 0, lanes 32..63 = head 1 -> width-16 xor-reduce per head.
// FUSED: epilogue computes sigmoid(relu(o) . w34 + b34) -> out[node] (1 float).

template<bool FUSED>
__global__ __launch_bounds__(256) void gat_agg(
    const float* __restrict__ xs, const float* __restrict__ xd,
    const float* __restrict__ att, const float* __restrict__ bias,
    const int* __restrict__ row_ptr, const int* __restrict__ csr_src,
    float* __restrict__ out, const float* __restrict__ w34, int n)
{
    int node = blockIdx.x * 4 + (threadIdx.x >> 6);
    if (node >= n) return;
    int lane = threadIdx.x & 63;
    int c = lane * 4;

    float4 xdv = *(const float4*)&xd[(size_t)node * 256 + c];
    float4 atv = *(const float4*)&att[c];

    float m = -INFINITY, l = 0.f;
    float4 acc = make_float4(0.f, 0.f, 0.f, 0.f);

    int s = row_ptr[node], e = row_ptr[node + 1];
    int deg = e - s;
    int my_src = (lane < deg) ? csr_src[s + lane] : 0;

    for (int i = -1; i < deg; ++i) {
        int srcn = (i < 0) ? node : ((i < 64) ? __shfl(my_src, i) : csr_src[s + i]);
        float4 xv = *(const float4*)&xs[(size_t)srcn * 256 + c];
        float v0 = xv.x + xdv.x; v0 = v0 > 0.f ? v0 : 0.2f * v0;
        float v1 = xv.y + xdv.y; v1 = v1 > 0.f ? v1 : 0.2f * v1;
        float v2 = xv.z + xdv.z; v2 = v2 > 0.f ? v2 : 0.2f * v2;
        float v3 = xv.w + xdv.w; v3 = v3 > 0.f ? v3 : 0.2f * v3;
        float p = v0 * atv.x + v1 * atv.y + v2 * atv.z + v3 * atv.w;
#pragma unroll
        for (int off = 16; off; off >>= 1) p += __shfl_xor(p, off);  // per-head sum
        float mn = fmaxf(m, p);
        float sc = __expf(m - mn);        // exp(-inf)=0 on first iteration
        float w  = __expf(p - mn);
        l = l * sc + w;
        acc.x = acc.x * sc + w * xv.x;
        acc.y = acc.y * sc + w * xv.y;
        acc.z = acc.z * sc + w * xv.z;
        acc.w = acc.w * sc + w * xv.w;
        m = mn;
    }
    float inv = 1.f / (l + 1e-16f);
    float4 bv = *(const float4*)&bias[c];
    float4 o;
    o.x = fmaxf(acc.x * inv + bv.x, 0.f);
    o.y = fmaxf(acc.y * inv + bv.y, 0.f);
    o.z = fmaxf(acc.z * inv + bv.z, 0.f);
    o.w = fmaxf(acc.w * inv + bv.w, 0.f);

    if (!FUSED) {
        *(float4*)&out[(size_t)node * 256 + c] = o;
    } else {
        float4 wv = *(const float4*)&w34[c];
        float p = o.x * wv.x + o.y * wv.y + o.z * wv.z + o.w * wv.w;
#pragma unroll
        for (int off = 32; off; off >>= 1) p += __shfl_xor(p, off);  // full-row sum
        if (lane == 0) out[node] = 1.f / (1.f + __expf(-(p + w34[256])));
    }
}

// ---------------------------------------------------------------------------

extern "C" void kernel_launch(void* const* d_in, const int* in_sizes, int n_in,
                              void* d_out, int out_size, void* d_ws, size_t ws_size,
                              hipStream_t stream)
{
    const float* x     = (const float*)d_in[0];
    const int*   ei    = (const int*)d_in[1];
    const float* Wl1   = (const float*)d_in[2];
    const float* bl1   = (const float*)d_in[3];
    const float* Wr1   = (const float*)d_in[4];
    const float* br1   = (const float*)d_in[5];
    const float* att1  = (const float*)d_in[6];
    const float* bias1 = (const float*)d_in[7];
    const float* Wl2   = (const float*)d_in[8];
    const float* bl2   = (const float*)d_in[9];
    const float* Wr2   = (const float*)d_in[10];
    const float* br2   = (const float*)d_in[11];
    const float* att2  = (const float*)d_in[12];
    const float* bias2 = (const float*)d_in[13];
    const float* W3    = (const float*)d_in[14];
    const float* b3    = (const float*)d_in[15];
    const float* W4    = (const float*)d_in[16];
    const float* b4    = (const float*)d_in[17];

    const int N = in_sizes[0] / 128;     // 50000
    const int E = in_sizes[1] / 2;       // 600000
    const int* src = ei;
    const int* dst = ei + E;

    char* ws = (char*)d_ws;
    float* xs      = (float*)(ws + 0);            // [N,256]
    float* xd      = (float*)(ws + 51200000);     // [N,256]
    float* h       = (float*)(ws + 102400000);    // [N,256]
    int*   row_ptr = (int*)(ws + 153600000);      // N+1
    int*   counts  = (int*)(ws + 153800192);      // N
    int*   cursor  = (int*)(ws + 154000384);      // N
    int*   csr_src = (int*)(ws + 154200576);      // E
    float* w34     = (float*)(ws + 156600576);    // 257

    // ---- CSR build ----
    hipMemsetAsync(counts, 0, N * sizeof(int), stream);
    count_edges<<<(E + 255) / 256, 256, 0, stream>>>(dst, counts, E);
    scan_kernel<<<1, 1024, 0, stream>>>(counts, row_ptr, cursor, N);
    scatter_edges<<<(E + 255) / 256, 256, 0, stream>>>(src, dst, cursor, csr_src, E);
    w34_kernel<<<65, 256, 0, stream>>>(W3, b3, W4, b4, w34);

    dim3 gN(256 / BN, (N + BM - 1) / BM);
    int aggBlocks = (N + 3) / 4;

    // ---- layer 1 ----
    sgemm_bias<<<gN, 256, 0, stream>>>(x, Wl1, bl1, xs, N, 256, 128);
    sgemm_bias<<<gN, 256, 0, stream>>>(x, Wr1, br1, xd, N, 256, 128);
    gat_agg<false><<<aggBlocks, 256, 0, stream>>>(xs, xd, att1, bias1, row_ptr, csr_src, h, nullptr, N);

    // ---- layer 2 (+ fused post-MLP) ----
    sgemm_bias<<<gN, 256, 0, stream>>>(h, Wl2, bl2, xs, N, 256, 256);
    sgemm_bias<<<gN, 256, 0, stream>>>(h, Wr2, br2, xd, N, 256, 256);
    gat_agg<true><<<aggBlocks, 256, 0, stream>>>(xs, xd, att2, bias2, row_ptr, csr_src,
                                                 (float*)d_out, w34, N);
}

// Round 8
// 497.459 us; speedup vs baseline: 1.8299x; 1.4089x over previous
//
#include <hip/hip_runtime.h>
#include <hip/hip_bf16.h>
#include <math.h>

// ---------------------------------------------------------------------------
// GATv2 x2 + fused MLP head.
//  R5: GEMMs -> bf16 MFMA (16x16x32, fp32 accum), one N=512 GEMM per layer
//      (Wl|Wr concatenated, W pre-transposed to [512][K] bf16).
//      global_load_lds(16B) staging, pre-swizzled source (slot ^= row&7).
//      gat_agg unchanged except strides (xsd[N][512]) + bf16 h output.
//  (resubmit: rounds 6-7 hit GPUAcquisitionTimeout, kernel never executed)
// ---------------------------------------------------------------------------

typedef short bf16x8 __attribute__((ext_vector_type(8)));
typedef float f32x4  __attribute__((ext_vector_type(4)));

#define TM 128
#define TN 128
#define GBK 64

__device__ inline void load_lds16(const void* g, void* l)
{
    __builtin_amdgcn_global_load_lds((const __attribute__((address_space(1))) void*)g,
                                     (__attribute__((address_space(3))) void*)l, 16, 0, 0);
}

// C[M][ldc] fp32 = A[M][K](bf16) . Bt[Nt][K](bf16)^T + bias. Rows of A padded to grid.
__global__ __launch_bounds__(256) void gemm_mfma(
    const __hip_bfloat16* __restrict__ A, const __hip_bfloat16* __restrict__ Bt,
    const float* __restrict__ bl, const float* __restrict__ br,
    float* __restrict__ C, int M, int K, int ldc)
{
    __shared__ char lsA[TM * GBK * 2];   // [row r][phys slot p]16B, p = logical ^ (r&7)
    __shared__ char lsB[TN * GBK * 2];

    int t = threadIdx.x;
    int w = t >> 6, l = t & 63;
    int row0 = blockIdx.y * TM;
    int col0 = blockIdx.x * TN;

    int wrow = (w >> 1) * 64, wcol = (w & 1) * 64;
    int lr = l & 15, lh = l >> 4;

    f32x4 acc[4][4] = {};

    for (int k0 = 0; k0 < K; k0 += GBK) {
        // stage A and Bt tiles: 1024 chunks of 16B each, linear LDS, swizzled source
#pragma unroll
        for (int c = 0; c < 4; ++c) {
            int i = c * 256 + t;
            int r = i >> 3, p = i & 7;
            int sl = p ^ (r & 7);
            load_lds16(A  + (size_t)(row0 + r) * K + k0 + sl * 8, lsA + (c * 256 + w * 64) * 16);
            load_lds16(Bt + (size_t)(col0 + r) * K + k0 + sl * 8, lsB + (c * 256 + w * 64) * 16);
        }
        __syncthreads();
#pragma unroll
        for (int kk = 0; kk < 2; ++kk) {
            bf16x8 af[4], bg[4];
#pragma unroll
            for (int m = 0; m < 4; ++m) {
                int r = wrow + m * 16 + lr;
                int sl = (kk * 4 + lh) ^ (r & 7);
                af[m] = *(const bf16x8*)(lsA + r * 128 + sl * 16);
            }
#pragma unroll
            for (int n = 0; n < 4; ++n) {
                int r = wcol + n * 16 + lr;
                int sl = (kk * 4 + lh) ^ (r & 7);
                bg[n] = *(const bf16x8*)(lsB + r * 128 + sl * 16);
            }
#pragma unroll
            for (int m = 0; m < 4; ++m)
#pragma unroll
                for (int n = 0; n < 4; ++n)
                    acc[m][n] = __builtin_amdgcn_mfma_f32_16x16x32_bf16(af[m], bg[n], acc[m][n], 0, 0, 0);
        }
        __syncthreads();
    }

    // epilogue: C/D layout col=lane&15, row=(lane>>4)*4+reg
#pragma unroll
    for (int n = 0; n < 4; ++n) {
        int col = col0 + wcol + n * 16 + lr;
        float bv = (col < 256) ? bl[col] : br[col - 256];
#pragma unroll
        for (int m = 0; m < 4; ++m) {
            int rbase = row0 + wrow + m * 16 + lh * 4;
#pragma unroll
            for (int j = 0; j < 4; ++j) {
                int row = rbase + j;
                if (row < M) C[(size_t)row * ldc + col] = acc[m][n][j] + bv;
            }
        }
    }
}

// ---------------------- weight / input prep (bf16) ---------------------------

// Wt[n][k] = (n<256 ? Wl[k][n] : Wr[k][n-256]), n in [0,512), bf16
__global__ void prep_wt(const float* __restrict__ Wl, const float* __restrict__ Wr,
                        __hip_bfloat16* __restrict__ Wt, int K)
{
    int idx = blockIdx.x * blockDim.x + threadIdx.x;
    if (idx >= 512 * K) return;
    int n = idx / K, k = idx - n * K;
    float v = (n < 256) ? Wl[(size_t)k * 256 + n] : Wr[(size_t)k * 256 + (n - 256)];
    Wt[idx] = __float2bfloat16(v);
}

__global__ void conv_bf16(const float* __restrict__ in, __hip_bfloat16* __restrict__ out, int n)
{
    int i = blockIdx.x * blockDim.x + threadIdx.x;
    if (i * 4 >= n) return;
    float4 v = *(const float4*)&in[i * 4];
    __hip_bfloat16 t0 = __float2bfloat16(v.x), t1 = __float2bfloat16(v.y);
    __hip_bfloat16 t2 = __float2bfloat16(v.z), t3 = __float2bfloat16(v.w);
    ushort4 pk = make_ushort4(*(unsigned short*)&t0, *(unsigned short*)&t1,
                              *(unsigned short*)&t2, *(unsigned short*)&t3);
    *(ushort4*)&out[(size_t)i * 4] = pk;
}

// ----------------------------- CSR construction -----------------------------

__global__ void count_edges(const int* __restrict__ dst, int* __restrict__ counts, int E)
{
    int i = blockIdx.x * blockDim.x + threadIdx.x;
    if (i < E) atomicAdd(&counts[dst[i]], 1);
}

__global__ __launch_bounds__(1024) void scan_kernel(
    const int* __restrict__ counts, int* __restrict__ row_ptr,
    int* __restrict__ cursor, int n)
{
    __shared__ int wsum[16];
    __shared__ int stot;
    int tid = threadIdx.x;
    int lane = tid & 63, wid = tid >> 6;
    int offset = 0;
    for (int base = 0; base < n; base += 1024) {
        int idx = base + tid;
        int v = (idx < n) ? counts[idx] : 0;
        int x = v;
#pragma unroll
        for (int off = 1; off < 64; off <<= 1) {
            int y = __shfl_up(x, off);
            if (lane >= off) x += y;
        }
        if (lane == 63) wsum[wid] = x;
        __syncthreads();
        if (tid == 0) {
            int run = 0;
#pragma unroll
            for (int i = 0; i < 16; ++i) { int tt = wsum[i]; wsum[i] = run; run += tt; }
            stot = run;
        }
        __syncthreads();
        int excl = offset + wsum[wid] + x - v;
        if (idx < n) { row_ptr[idx] = excl; cursor[idx] = excl; }
        offset += stot;
        __syncthreads();
    }
    if (tid == 0) row_ptr[n] = offset;
}

__global__ void scatter_edges(const int* __restrict__ src, const int* __restrict__ dst,
                              int* __restrict__ cursor, int* __restrict__ csr_src, int E)
{
    int i = blockIdx.x * blockDim.x + threadIdx.x;
    if (i < E) {
        int pos = atomicAdd(&cursor[dst[i]], 1);
        csr_src[pos] = src[i];
    }
}

// ------------------------- W34 = W3 @ W4 fold --------------------------------
__global__ __launch_bounds__(256) void w34_kernel(
    const float* __restrict__ W3, const float* __restrict__ b3,
    const float* __restrict__ W4, const float* __restrict__ b4,
    float* __restrict__ w34)
{
    int wid = blockIdx.x * 4 + (threadIdx.x >> 6);
    int lane = threadIdx.x & 63;
    if (wid > 256) return;
    const float* row = (wid < 256) ? &W3[(size_t)wid * 128] : b3;
    float p = row[lane] * W4[lane] + row[lane + 64] * W4[lane + 64];
#pragma unroll
    for (int off = 32; off; off >>= 1) p += __shfl_xor(p, off);
    if (lane == 0) w34[wid] = (wid < 256) ? p : (p + b4[0]);
}

// ------------------------- per-node aggregation ------------------------------
// xsd[n][512]: xs = cols [0,256), xd = cols [256,512). One wave per node.
// !FUSED: writes h as bf16 [n][256] (layer-2 GEMM A operand).
//  FUSED: writes sigmoid(relu(o) . w34 + b34) -> outf[node].

template<bool FUSED>
__global__ __launch_bounds__(256) void gat_agg(
    const float* __restrict__ xsd,
    const float* __restrict__ att, const float* __restrict__ bias,
    const int* __restrict__ row_ptr, const int* __restrict__ csr_src,
    __hip_bfloat16* __restrict__ outb, float* __restrict__ outf,
    const float* __restrict__ w34, int n)
{
    int node = blockIdx.x * 4 + (threadIdx.x >> 6);
    if (node >= n) return;
    int lane = threadIdx.x & 63;
    int c = lane * 4;

    float4 xdv = *(const float4*)&xsd[(size_t)node * 512 + 256 + c];
    float4 atv = *(const float4*)&att[c];

    float m = -INFINITY, l = 0.f;
    float4 acc = make_float4(0.f, 0.f, 0.f, 0.f);

    int s = row_ptr[node], e = row_ptr[node + 1];
    int deg = e - s;
    int my_src = (lane < deg) ? csr_src[s + lane] : 0;

    for (int i = -1; i < deg; ++i) {
        int srcn = (i < 0) ? node : ((i < 64) ? __shfl(my_src, i) : csr_src[s + i]);
        float4 xv = *(const float4*)&xsd[(size_t)srcn * 512 + c];
        float v0 = xv.x + xdv.x; v0 = v0 > 0.f ? v0 : 0.2f * v0;
        float v1 = xv.y + xdv.y; v1 = v1 > 0.f ? v1 : 0.2f * v1;
        float v2 = xv.z + xdv.z; v2 = v2 > 0.f ? v2 : 0.2f * v2;
        float v3 = xv.w + xdv.w; v3 = v3 > 0.f ? v3 : 0.2f * v3;
        float p = v0 * atv.x + v1 * atv.y + v2 * atv.z + v3 * atv.w;
#pragma unroll
        for (int off = 16; off; off >>= 1) p += __shfl_xor(p, off);  // per-head sum
        float mn = fmaxf(m, p);
        float sc = __expf(m - mn);
        float wgt = __expf(p - mn);
        l = l * sc + wgt;
        acc.x = acc.x * sc + wgt * xv.x;
        acc.y = acc.y * sc + wgt * xv.y;
        acc.z = acc.z * sc + wgt * xv.z;
        acc.w = acc.w * sc + wgt * xv.w;
        m = mn;
    }
    float inv = 1.f / (l + 1e-16f);
    float4 bv = *(const float4*)&bias[c];
    float4 o;
    o.x = fmaxf(acc.x * inv + bv.x, 0.f);
    o.y = fmaxf(acc.y * inv + bv.y, 0.f);
    o.z = fmaxf(acc.z * inv + bv.z, 0.f);
    o.w = fmaxf(acc.w * inv + bv.w, 0.f);

    if (!FUSED) {
        __hip_bfloat16 t0 = __float2bfloat16(o.x), t1 = __float2bfloat16(o.y);
        __hip_bfloat16 t2 = __float2bfloat16(o.z), t3 = __float2bfloat16(o.w);
        ushort4 pk = make_ushort4(*(unsigned short*)&t0, *(unsigned short*)&t1,
                                  *(unsigned short*)&t2, *(unsigned short*)&t3);
        *(ushort4*)&outb[(size_t)node * 256 + c] = pk;
    } else {
        float4 wv = *(const float4*)&w34[c];
        float p = o.x * wv.x + o.y * wv.y + o.z * wv.z + o.w * wv.w;
#pragma unroll
        for (int off = 32; off; off >>= 1) p += __shfl_xor(p, off);
        if (lane == 0) outf[node] = 1.f / (1.f + __expf(-(p + w34[256])));
    }
}

// ---------------------------------------------------------------------------

extern "C" void kernel_launch(void* const* d_in, const int* in_sizes, int n_in,
                              void* d_out, int out_size, void* d_ws, size_t ws_size,
                              hipStream_t stream)
{
    const float* x     = (const float*)d_in[0];
    const int*   ei    = (const int*)d_in[1];
    const float* Wl1   = (const float*)d_in[2];
    const float* bl1   = (const float*)d_in[3];
    const float* Wr1   = (const float*)d_in[4];
    const float* br1   = (const float*)d_in[5];
    const float* att1  = (const float*)d_in[6];
    const float* bias1 = (const float*)d_in[7];
    const float* Wl2   = (const float*)d_in[8];
    const float* bl2   = (const float*)d_in[9];
    const float* Wr2   = (const float*)d_in[10];
    const float* br2   = (const float*)d_in[11];
    const float* att2  = (const float*)d_in[12];
    const float* bias2 = (const float*)d_in[13];
    const float* W3    = (const float*)d_in[14];
    const float* b3    = (const float*)d_in[15];
    const float* W4    = (const float*)d_in[16];
    const float* b4    = (const float*)d_in[17];

    const int N = in_sizes[0] / 128;     // 50000
    const int E = in_sizes[1] / 2;       // 600000
    const int Mp = ((N + TM - 1) / TM) * TM;   // 50048 padded rows
    const int* src = ei;
    const int* dst = ei + E;

    char* ws = (char*)d_ws;
    float*          xsd     = (float*)(ws + 0);                    // [N][512] fp32, 102.4 MB
    __hip_bfloat16* xbf     = (__hip_bfloat16*)(ws + 102400000);   // [Mp][128] bf16
    __hip_bfloat16* hbf     = (__hip_bfloat16*)(ws + 115212544);   // [Mp][256] bf16
    __hip_bfloat16* Wt1     = (__hip_bfloat16*)(ws + 140837120);   // [512][128] bf16
    __hip_bfloat16* Wt2     = (__hip_bfloat16*)(ws + 140968192);   // [512][256] bf16
    int*            row_ptr = (int*)(ws + 141230336);              // N+1
    int*            counts  = (int*)(ws + 141430400);              // N
    int*            cursor  = (int*)(ws + 141630400);              // N
    int*            csr_src = (int*)(ws + 141830400);              // E
    float*          w34     = (float*)(ws + 144230400);            // 257

    // ---- CSR build + weight prep (independent of GEMMs) ----
    hipMemsetAsync(counts, 0, N * sizeof(int), stream);
    count_edges<<<(E + 255) / 256, 256, 0, stream>>>(dst, counts, E);
    scan_kernel<<<1, 1024, 0, stream>>>(counts, row_ptr, cursor, N);
    scatter_edges<<<(E + 255) / 256, 256, 0, stream>>>(src, dst, cursor, csr_src, E);
    w34_kernel<<<65, 256, 0, stream>>>(W3, b3, W4, b4, w34);
    prep_wt<<<(512 * 128 + 255) / 256, 256, 0, stream>>>(Wl1, Wr1, Wt1, 128);
    prep_wt<<<(512 * 256 + 255) / 256, 256, 0, stream>>>(Wl2, Wr2, Wt2, 256);
    conv_bf16<<<(N * 128 / 4 + 255) / 256, 256, 0, stream>>>(x, xbf, N * 128);

    dim3 gemmGrid(512 / TN, Mp / TM);
    int aggBlocks = (N + 3) / 4;

    // ---- layer 1: xsd[:, :256]=x@Wl1+bl1, xsd[:, 256:]=x@Wr1+br1 ----
    gemm_mfma<<<gemmGrid, 256, 0, stream>>>(xbf, Wt1, bl1, br1, xsd, N, 128, 512);
    gat_agg<false><<<aggBlocks, 256, 0, stream>>>(xsd, att1, bias1, row_ptr, csr_src,
                                                  hbf, nullptr, nullptr, N);

    // ---- layer 2 (+ fused post-MLP) ----
    gemm_mfma<<<gemmGrid, 256, 0, stream>>>(hbf, Wt2, bl2, br2, xsd, N, 256, 512);
    gat_agg<true><<<aggBlocks, 256, 0, stream>>>(xsd, att2, bias2, row_ptr, csr_src,
                                                 nullptr, (float*)d_out, w34, N);
}

// Round 10
// 476.541 us; speedup vs baseline: 1.9102x; 1.0439x over previous
//
#include <hip/hip_runtime.h>
#include <hip/hip_bf16.h>
#include <hip/hip_fp16.h>
#include <math.h>

// ---------------------------------------------------------------------------
// GATv2 x2 + fused MLP head.
//  R8: xs stored fp16 (halves edge-gather bytes; fp16 not bf16 for 8x less
//      rounding), xd fp32 separate array; GEMM epilogue writes both directly.
//      Defer-max online softmax (THR=8) skips rescale on common path.
//  (resubmit: round-9 hit GPUAcquisitionTimeout, kernel never executed)
// ---------------------------------------------------------------------------

typedef short bf16x8 __attribute__((ext_vector_type(8)));
typedef float f32x4  __attribute__((ext_vector_type(4)));

#define TM 128
#define TN 128
#define GBK 64

__device__ inline void load_lds16(const void* g, void* l)
{
    __builtin_amdgcn_global_load_lds((const __attribute__((address_space(1))) void*)g,
                                     (__attribute__((address_space(3))) void*)l, 16, 0, 0);
}

// xs cols [0,256) -> xsh fp16 [M][256]; xd cols [256,512) -> xd fp32 [M][256].
// A[M][K] bf16, Bt[512][K] bf16 (pre-transposed). fp32 MFMA accumulate.
__global__ __launch_bounds__(256) void gemm_mfma(
    const __hip_bfloat16* __restrict__ A, const __hip_bfloat16* __restrict__ Bt,
    const float* __restrict__ bl, const float* __restrict__ br,
    _Float16* __restrict__ xsh, float* __restrict__ xd,
    int M, int K)
{
    __shared__ char lsA[TM * GBK * 2];   // [row r][phys slot p]16B, p = logical ^ (r&7)
    __shared__ char lsB[TN * GBK * 2];

    int t = threadIdx.x;
    int w = t >> 6, l = t & 63;
    int row0 = blockIdx.y * TM;
    int col0 = blockIdx.x * TN;

    int wrow = (w >> 1) * 64, wcol = (w & 1) * 64;
    int lr = l & 15, lh = l >> 4;

    f32x4 acc[4][4] = {};

    for (int k0 = 0; k0 < K; k0 += GBK) {
#pragma unroll
        for (int c = 0; c < 4; ++c) {
            int i = c * 256 + t;
            int r = i >> 3, p = i & 7;
            int sl = p ^ (r & 7);
            load_lds16(A  + (size_t)(row0 + r) * K + k0 + sl * 8, lsA + (c * 256 + w * 64) * 16);
            load_lds16(Bt + (size_t)(col0 + r) * K + k0 + sl * 8, lsB + (c * 256 + w * 64) * 16);
        }
        __syncthreads();
#pragma unroll
        for (int kk = 0; kk < 2; ++kk) {
            bf16x8 af[4], bg[4];
#pragma unroll
            for (int m = 0; m < 4; ++m) {
                int r = wrow + m * 16 + lr;
                int sl = (kk * 4 + lh) ^ (r & 7);
                af[m] = *(const bf16x8*)(lsA + r * 128 + sl * 16);
            }
#pragma unroll
            for (int n = 0; n < 4; ++n) {
                int r = wcol + n * 16 + lr;
                int sl = (kk * 4 + lh) ^ (r & 7);
                bg[n] = *(const bf16x8*)(lsB + r * 128 + sl * 16);
            }
#pragma unroll
            for (int m = 0; m < 4; ++m)
#pragma unroll
                for (int n = 0; n < 4; ++n)
                    acc[m][n] = __builtin_amdgcn_mfma_f32_16x16x32_bf16(af[m], bg[n], acc[m][n], 0, 0, 0);
        }
        __syncthreads();
    }

    // C/D layout: col=lane&15, row=(lane>>4)*4+reg. col-blocks 0,1 -> xs; 2,3 -> xd.
    bool is_xs = (col0 < 256);
#pragma unroll
    for (int n = 0; n < 4; ++n) {
        int col = col0 + wcol + n * 16 + lr;
        float bv = is_xs ? bl[col] : br[col - 256];
#pragma unroll
        for (int m = 0; m < 4; ++m) {
            int rbase = row0 + wrow + m * 16 + lh * 4;
#pragma unroll
            for (int j = 0; j < 4; ++j) {
                int row = rbase + j;
                if (row < M) {
                    float v = acc[m][n][j] + bv;
                    if (is_xs) xsh[(size_t)row * 256 + col] = (_Float16)v;
                    else       xd [(size_t)row * 256 + col - 256] = v;
                }
            }
        }
    }
}

// ---------------------- weight / input prep (bf16) ---------------------------

__global__ void prep_wt(const float* __restrict__ Wl, const float* __restrict__ Wr,
                        __hip_bfloat16* __restrict__ Wt, int K)
{
    int idx = blockIdx.x * blockDim.x + threadIdx.x;
    if (idx >= 512 * K) return;
    int n = idx / K, k = idx - n * K;
    float v = (n < 256) ? Wl[(size_t)k * 256 + n] : Wr[(size_t)k * 256 + (n - 256)];
    Wt[idx] = __float2bfloat16(v);
}

__global__ void conv_bf16(const float* __restrict__ in, __hip_bfloat16* __restrict__ out, int n)
{
    int i = blockIdx.x * blockDim.x + threadIdx.x;
    if (i * 4 >= n) return;
    float4 v = *(const float4*)&in[i * 4];
    __hip_bfloat16 t0 = __float2bfloat16(v.x), t1 = __float2bfloat16(v.y);
    __hip_bfloat16 t2 = __float2bfloat16(v.z), t3 = __float2bfloat16(v.w);
    ushort4 pk = make_ushort4(*(unsigned short*)&t0, *(unsigned short*)&t1,
                              *(unsigned short*)&t2, *(unsigned short*)&t3);
    *(ushort4*)&out[(size_t)i * 4] = pk;
}

// ----------------------------- CSR construction -----------------------------

__global__ void count_edges(const int* __restrict__ dst, int* __restrict__ counts, int E)
{
    int i = blockIdx.x * blockDim.x + threadIdx.x;
    if (i < E) atomicAdd(&counts[dst[i]], 1);
}

__global__ __launch_bounds__(1024) void scan_kernel(
    const int* __restrict__ counts, int* __restrict__ row_ptr,
    int* __restrict__ cursor, int n)
{
    __shared__ int wsum[16];
    __shared__ int stot;
    int tid = threadIdx.x;
    int lane = tid & 63, wid = tid >> 6;
    int offset = 0;
    for (int base = 0; base < n; base += 1024) {
        int idx = base + tid;
        int v = (idx < n) ? counts[idx] : 0;
        int x = v;
#pragma unroll
        for (int off = 1; off < 64; off <<= 1) {
            int y = __shfl_up(x, off);
            if (lane >= off) x += y;
        }
        if (lane == 63) wsum[wid] = x;
        __syncthreads();
        if (tid == 0) {
            int run = 0;
#pragma unroll
            for (int i = 0; i < 16; ++i) { int tt = wsum[i]; wsum[i] = run; run += tt; }
            stot = run;
        }
        __syncthreads();
        int excl = offset + wsum[wid] + x - v;
        if (idx < n) { row_ptr[idx] = excl; cursor[idx] = excl; }
        offset += stot;
        __syncthreads();
    }
    if (tid == 0) row_ptr[n] = offset;
}

__global__ void scatter_edges(const int* __restrict__ src, const int* __restrict__ dst,
                              int* __restrict__ cursor, int* __restrict__ csr_src, int E)
{
    int i = blockIdx.x * blockDim.x + threadIdx.x;
    if (i < E) {
        int pos = atomicAdd(&cursor[dst[i]], 1);
        csr_src[pos] = src[i];
    }
}

// ------------------------- W34 = W3 @ W4 fold --------------------------------
__global__ __launch_bounds__(256) void w34_kernel(
    const float* __restrict__ W3, const float* __restrict__ b3,
    const float* __restrict__ W4, const float* __restrict__ b4,
    float* __restrict__ w34)
{
    int wid = blockIdx.x * 4 + (threadIdx.x >> 6);
    int lane = threadIdx.x & 63;
    if (wid > 256) return;
    const float* row = (wid < 256) ? &W3[(size_t)wid * 128] : b3;
    float p = row[lane] * W4[lane] + row[lane + 64] * W4[lane + 64];
#pragma unroll
    for (int off = 32; off; off >>= 1) p += __shfl_xor(p, off);
    if (lane == 0) w34[wid] = (wid < 256) ? p : (p + b4[0]);
}

// ------------------------- per-node aggregation ------------------------------
// One wave per node. lane L owns dims 4L..4L+3 of 256 (head0 lanes 0-31,
// head1 lanes 32-63). xs gathered fp16, xd fp32. Defer-max online softmax:
// while all p <= m+8, keep m (no rescale); weights bounded by e^8.

template<bool FUSED>
__global__ __launch_bounds__(256) void gat_agg(
    const _Float16* __restrict__ xsh, const float* __restrict__ xd,
    const float* __restrict__ att, const float* __restrict__ bias,
    const int* __restrict__ row_ptr, const int* __restrict__ csr_src,
    __hip_bfloat16* __restrict__ outb, float* __restrict__ outf,
    const float* __restrict__ w34, int n)
{
    int node = blockIdx.x * 4 + (threadIdx.x >> 6);
    if (node >= n) return;
    int lane = threadIdx.x & 63;
    int c = lane * 4;

    float4 xdv = *(const float4*)&xd[(size_t)node * 256 + c];
    float4 atv = *(const float4*)&att[c];

    float m = -INFINITY, l = 0.f;
    float4 acc = make_float4(0.f, 0.f, 0.f, 0.f);

    int s = row_ptr[node], e = row_ptr[node + 1];
    int deg = e - s;
    int my_src = (lane < deg) ? csr_src[s + lane] : 0;

    for (int i = -1; i < deg; ++i) {
        int srcn = (i < 0) ? node : ((i < 64) ? __shfl(my_src, i) : csr_src[s + i]);
        ushort4 us = *(const ushort4*)&xsh[(size_t)srcn * 256 + c];
        float x0 = (float)(*(const _Float16*)&us.x);
        float x1 = (float)(*(const _Float16*)&us.y);
        float x2 = (float)(*(const _Float16*)&us.z);
        float x3 = (float)(*(const _Float16*)&us.w);
        float v0 = x0 + xdv.x; v0 = v0 > 0.f ? v0 : 0.2f * v0;
        float v1 = x1 + xdv.y; v1 = v1 > 0.f ? v1 : 0.2f * v1;
        float v2 = x2 + xdv.z; v2 = v2 > 0.f ? v2 : 0.2f * v2;
        float v3 = x3 + xdv.w; v3 = v3 > 0.f ? v3 : 0.2f * v3;
        float p = v0 * atv.x + v1 * atv.y + v2 * atv.z + v3 * atv.w;
#pragma unroll
        for (int off = 16; off; off >>= 1) p += __shfl_xor(p, off);  // per-head sum

        float pm = p - m;                       // first iter: +inf -> full path
        if (__all(pm <= 8.f)) {
            float wgt = __expf(pm);
            l += wgt;
            acc.x += wgt * x0;
            acc.y += wgt * x1;
            acc.z += wgt * x2;
            acc.w += wgt * x3;
        } else {
            float mn = fmaxf(m, p);
            float sc = __expf(m - mn);          // exp(-inf)=0 on first iteration
            float wgt = __expf(p - mn);
            l = l * sc + wgt;
            acc.x = acc.x * sc + wgt * x0;
            acc.y = acc.y * sc + wgt * x1;
            acc.z = acc.z * sc + wgt * x2;
            acc.w = acc.w * sc + wgt * x3;
            m = mn;
        }
    }
    float inv = 1.f / (l + 1e-16f);
    float4 bv = *(const float4*)&bias[c];
    float4 o;
    o.x = fmaxf(acc.x * inv + bv.x, 0.f);
    o.y = fmaxf(acc.y * inv + bv.y, 0.f);
    o.z = fmaxf(acc.z * inv + bv.z, 0.f);
    o.w = fmaxf(acc.w * inv + bv.w, 0.f);

    if (!FUSED) {
        __hip_bfloat16 t0 = __float2bfloat16(o.x), t1 = __float2bfloat16(o.y);
        __hip_bfloat16 t2 = __float2bfloat16(o.z), t3 = __float2bfloat16(o.w);
        ushort4 pk = make_ushort4(*(unsigned short*)&t0, *(unsigned short*)&t1,
                                  *(unsigned short*)&t2, *(unsigned short*)&t3);
        *(ushort4*)&outb[(size_t)node * 256 + c] = pk;
    } else {
        float4 wv = *(const float4*)&w34[c];
        float p = o.x * wv.x + o.y * wv.y + o.z * wv.z + o.w * wv.w;
#pragma unroll
        for (int off = 32; off; off >>= 1) p += __shfl_xor(p, off);
        if (lane == 0) outf[node] = 1.f / (1.f + __expf(-(p + w34[256])));
    }
}

// ---------------------------------------------------------------------------

extern "C" void kernel_launch(void* const* d_in, const int* in_sizes, int n_in,
                              void* d_out, int out_size, void* d_ws, size_t ws_size,
                              hipStream_t stream)
{
    const float* x     = (const float*)d_in[0];
    const int*   ei    = (const int*)d_in[1];
    const float* Wl1   = (const float*)d_in[2];
    const float* bl1   = (const float*)d_in[3];
    const float* Wr1   = (const float*)d_in[4];
    const float* br1   = (const float*)d_in[5];
    const float* att1  = (const float*)d_in[6];
    const float* bias1 = (const float*)d_in[7];
    const float* Wl2   = (const float*)d_in[8];
    const float* bl2   = (const float*)d_in[9];
    const float* Wr2   = (const float*)d_in[10];
    const float* br2   = (const float*)d_in[11];
    const float* att2  = (const float*)d_in[12];
    const float* bias2 = (const float*)d_in[13];
    const float* W3    = (const float*)d_in[14];
    const float* b3    = (const float*)d_in[15];
    const float* W4    = (const float*)d_in[16];
    const float* b4    = (const float*)d_in[17];

    const int N = in_sizes[0] / 128;     // 50000
    const int E = in_sizes[1] / 2;       // 600000
    const int Mp = ((N + TM - 1) / TM) * TM;   // 50048 padded rows
    const int* src = ei;
    const int* dst = ei + E;

    char* ws = (char*)d_ws;
    _Float16*       xsh     = (_Float16*)(ws + 0);                 // [N][256] fp16, 25.6 MB
    float*          xd      = (float*)(ws + 25600000);             // [N][256] fp32, 51.2 MB
    __hip_bfloat16* xbf     = (__hip_bfloat16*)(ws + 76800000);    // [Mp][128] bf16
    __hip_bfloat16* hbf     = (__hip_bfloat16*)(ws + 89612288);    // [Mp][256] bf16
    __hip_bfloat16* Wt1     = (__hip_bfloat16*)(ws + 115236864);   // [512][128] bf16
    __hip_bfloat16* Wt2     = (__hip_bfloat16*)(ws + 115367936);   // [512][256] bf16
    int*            row_ptr = (int*)(ws + 115630080);              // N+1
    int*            counts  = (int*)(ws + 115830144);              // N
    int*            cursor  = (int*)(ws + 116030144);              // N
    int*            csr_src = (int*)(ws + 116230144);              // E
    float*          w34     = (float*)(ws + 118630144);            // 257

    // ---- CSR build + weight prep ----
    hipMemsetAsync(counts, 0, N * sizeof(int), stream);
    count_edges<<<(E + 255) / 256, 256, 0, stream>>>(dst, counts, E);
    scan_kernel<<<1, 1024, 0, stream>>>(counts, row_ptr, cursor, N);
    scatter_edges<<<(E + 255) / 256, 256, 0, stream>>>(src, dst, cursor, csr_src, E);
    w34_kernel<<<65, 256, 0, stream>>>(W3, b3, W4, b4, w34);
    prep_wt<<<(512 * 128 + 255) / 256, 256, 0, stream>>>(Wl1, Wr1, Wt1, 128);
    prep_wt<<<(512 * 256 + 255) / 256, 256, 0, stream>>>(Wl2, Wr2, Wt2, 256);
    conv_bf16<<<(N * 128 / 4 + 255) / 256, 256, 0, stream>>>(x, xbf, N * 128);

    dim3 gemmGrid(512 / TN, Mp / TM);
    int aggBlocks = (N + 3) / 4;

    // ---- layer 1 ----
    gemm_mfma<<<gemmGrid, 256, 0, stream>>>(xbf, Wt1, bl1, br1, xsh, xd, N, 128);
    gat_agg<false><<<aggBlocks, 256, 0, stream>>>(xsh, xd, att1, bias1, row_ptr, csr_src,
                                                  hbf, nullptr, nullptr, N);

    // ---- layer 2 (+ fused post-MLP) ----
    gemm_mfma<<<gemmGrid, 256, 0, stream>>>(hbf, Wt2, bl2, br2, xsh, xd, N, 256);
    gat_agg<true><<<aggBlocks, 256, 0, stream>>>(xsh, xd, att2, bias2, row_ptr, csr_src,
                                                 nullptr, (float*)d_out, w34, N);
}

// Round 12
// 416.771 us; speedup vs baseline: 2.1842x; 1.1434x over previous
//
#include <hip/hip_runtime.h>
#include <hip/hip_bf16.h>
#include <hip/hip_fp16.h>
#include <math.h>

// ---------------------------------------------------------------------------
// GATv2 x2 + fused MLP head.
//  R10: gat_agg processes 2 edges/iter (two 32-lane halves, 8 dims/lane,
//       16B fp16 gathers, end-merge via shfl_xor 32). gemm_mfma epilogue
//       staged through LDS for full-line coalesced writes (was 1.8x amplified).
//  (resubmit: round-11 hit GPUAcquisitionTimeout, kernel never executed)
// ---------------------------------------------------------------------------

typedef short    bf16x8 __attribute__((ext_vector_type(8)));
typedef float    f32x4  __attribute__((ext_vector_type(4)));
typedef _Float16 f16x8  __attribute__((ext_vector_type(8)));
typedef _Float16 f16x4  __attribute__((ext_vector_type(4)));

#define TM 128
#define TN 128
#define GBK 64

__device__ inline void load_lds16(const void* g, void* l)
{
    __builtin_amdgcn_global_load_lds((const __attribute__((address_space(1))) void*)g,
                                     (__attribute__((address_space(3))) void*)l, 16, 0, 0);
}

// xs cols [0,256) -> xsh fp16 [M][256]; xd cols [256,512) -> xd fp32 [M][256].
// A[M][K] bf16, Bt[512][K] bf16 (pre-transposed). fp32 MFMA accumulate.
__global__ __launch_bounds__(256) void gemm_mfma(
    const __hip_bfloat16* __restrict__ A, const __hip_bfloat16* __restrict__ Bt,
    const float* __restrict__ bl, const float* __restrict__ br,
    _Float16* __restrict__ xsh, float* __restrict__ xd,
    int M, int K)
{
    __shared__ char smem[32768];
    char* lsA = smem;             // [row r][phys slot p]16B, p = logical ^ (r&7)
    char* lsB = smem + 16384;

    int t = threadIdx.x;
    int w = t >> 6, l = t & 63;
    int row0 = blockIdx.y * TM;
    int col0 = blockIdx.x * TN;

    int wrow = (w >> 1) * 64, wcol = (w & 1) * 64;
    int lr = l & 15, lh = l >> 4;

    f32x4 acc[4][4] = {};

    for (int k0 = 0; k0 < K; k0 += GBK) {
#pragma unroll
        for (int c = 0; c < 4; ++c) {
            int i = c * 256 + t;
            int r = i >> 3, p = i & 7;
            int sl = p ^ (r & 7);
            load_lds16(A  + (size_t)(row0 + r) * K + k0 + sl * 8, lsA + (c * 256 + w * 64) * 16);
            load_lds16(Bt + (size_t)(col0 + r) * K + k0 + sl * 8, lsB + (c * 256 + w * 64) * 16);
        }
        __syncthreads();
#pragma unroll
        for (int kk = 0; kk < 2; ++kk) {
            bf16x8 af[4], bg[4];
#pragma unroll
            for (int mm = 0; mm < 4; ++mm) {
                int r = wrow + mm * 16 + lr;
                int sl = (kk * 4 + lh) ^ (r & 7);
                af[mm] = *(const bf16x8*)(lsA + r * 128 + sl * 16);
            }
#pragma unroll
            for (int nn = 0; nn < 4; ++nn) {
                int r = wcol + nn * 16 + lr;
                int sl = (kk * 4 + lh) ^ (r & 7);
                bg[nn] = *(const bf16x8*)(lsB + r * 128 + sl * 16);
            }
#pragma unroll
            for (int mm = 0; mm < 4; ++mm)
#pragma unroll
                for (int nn = 0; nn < 4; ++nn)
                    acc[mm][nn] = __builtin_amdgcn_mfma_f32_16x16x32_bf16(af[mm], bg[nn], acc[mm][nn], 0, 0, 0);
        }
        __syncthreads();
    }

    // LDS-staged epilogue: two passes of 64 rows x 128 cols (32 KB), then
    // coalesced full-line global stores with bias add (+fp16 convert for xs).
    float* stg = (float*)smem;
    bool is_xs = (col0 < 256);
    int cb = (t & 31) * 4;          // col 0..124
    int rb = t >> 5;                // row 0..7
    float4 bv = is_xs ? *(const float4*)&bl[col0 + cb]
                      : *(const float4*)&br[col0 + cb - 256];

#pragma unroll
    for (int pass = 0; pass < 2; ++pass) {
        if ((w >> 1) == pass) {
#pragma unroll
            for (int mm = 0; mm < 4; ++mm)
#pragma unroll
                for (int nn = 0; nn < 4; ++nn)
#pragma unroll
                    for (int j = 0; j < 4; ++j) {
                        int rl = mm * 16 + lh * 4 + j;     // 0..63
                        int cl = wcol + nn * 16 + lr;      // 0..127
                        stg[rl * 128 + cl] = acc[mm][nn][j];
                    }
        }
        __syncthreads();
#pragma unroll
        for (int sw = 0; sw < 8; ++sw) {
            int rl = rb + sw * 8;
            int grow = row0 + pass * 64 + rl;
            if (grow < M) {
                float4 v = *(float4*)&stg[rl * 128 + cb];
                v.x += bv.x; v.y += bv.y; v.z += bv.z; v.w += bv.w;
                int gcol = col0 + cb;
                if (is_xs) {
                    f16x4 hvv = { (_Float16)v.x, (_Float16)v.y, (_Float16)v.z, (_Float16)v.w };
                    *(f16x4*)&xsh[(size_t)grow * 256 + gcol] = hvv;
                } else {
                    *(float4*)&xd[(size_t)grow * 256 + gcol - 256] = v;
                }
            }
        }
        __syncthreads();
    }
}

// ---------------------- weight / input prep (bf16) ---------------------------

__global__ void prep_wt(const float* __restrict__ Wl, const float* __restrict__ Wr,
                        __hip_bfloat16* __restrict__ Wt, int K)
{
    int idx = blockIdx.x * blockDim.x + threadIdx.x;
    if (idx >= 512 * K) return;
    int n = idx / K, k = idx - n * K;
    float v = (n < 256) ? Wl[(size_t)k * 256 + n] : Wr[(size_t)k * 256 + (n - 256)];
    Wt[idx] = __float2bfloat16(v);
}

__global__ void conv_bf16(const float* __restrict__ in, __hip_bfloat16* __restrict__ out, int n)
{
    int i = blockIdx.x * blockDim.x + threadIdx.x;
    if (i * 4 >= n) return;
    float4 v = *(const float4*)&in[i * 4];
    __hip_bfloat16 t0 = __float2bfloat16(v.x), t1 = __float2bfloat16(v.y);
    __hip_bfloat16 t2 = __float2bfloat16(v.z), t3 = __float2bfloat16(v.w);
    ushort4 pk = make_ushort4(*(unsigned short*)&t0, *(unsigned short*)&t1,
                              *(unsigned short*)&t2, *(unsigned short*)&t3);
    *(ushort4*)&out[(size_t)i * 4] = pk;
}

// ----------------------------- CSR construction -----------------------------

__global__ void count_edges(const int* __restrict__ dst, int* __restrict__ counts, int E)
{
    int i = blockIdx.x * blockDim.x + threadIdx.x;
    if (i < E) atomicAdd(&counts[dst[i]], 1);
}

__global__ __launch_bounds__(1024) void scan_kernel(
    const int* __restrict__ counts, int* __restrict__ row_ptr,
    int* __restrict__ cursor, int n)
{
    __shared__ int wsum[16];
    __shared__ int stot;
    int tid = threadIdx.x;
    int lane = tid & 63, wid = tid >> 6;
    int offset = 0;
    for (int base = 0; base < n; base += 1024) {
        int idx = base + tid;
        int v = (idx < n) ? counts[idx] : 0;
        int x = v;
#pragma unroll
        for (int off = 1; off < 64; off <<= 1) {
            int y = __shfl_up(x, off);
            if (lane >= off) x += y;
        }
        if (lane == 63) wsum[wid] = x;
        __syncthreads();
        if (tid == 0) {
            int run = 0;
#pragma unroll
            for (int i = 0; i < 16; ++i) { int tt = wsum[i]; wsum[i] = run; run += tt; }
            stot = run;
        }
        __syncthreads();
        int excl = offset + wsum[wid] + x - v;
        if (idx < n) { row_ptr[idx] = excl; cursor[idx] = excl; }
        offset += stot;
        __syncthreads();
    }
    if (tid == 0) row_ptr[n] = offset;
}

__global__ void scatter_edges(const int* __restrict__ src, const int* __restrict__ dst,
                              int* __restrict__ cursor, int* __restrict__ csr_src, int E)
{
    int i = blockIdx.x * blockDim.x + threadIdx.x;
    if (i < E) {
        int pos = atomicAdd(&cursor[dst[i]], 1);
        csr_src[pos] = src[i];
    }
}

// ------------------------- W34 = W3 @ W4 fold --------------------------------
__global__ __launch_bounds__(256) void w34_kernel(
    const float* __restrict__ W3, const float* __restrict__ b3,
    const float* __restrict__ W4, const float* __restrict__ b4,
    float* __restrict__ w34)
{
    int wid = blockIdx.x * 4 + (threadIdx.x >> 6);
    int lane = threadIdx.x & 63;
    if (wid > 256) return;
    const float* row = (wid < 256) ? &W3[(size_t)wid * 128] : b3;
    float p = row[lane] * W4[lane] + row[lane + 64] * W4[lane + 64];
#pragma unroll
    for (int off = 32; off; off >>= 1) p += __shfl_xor(p, off);
    if (lane == 0) w34[wid] = (wid < 256) ? p : (p + b4[0]);
}

// ------------------------- per-node aggregation ------------------------------
// One wave per node, 2 edge-items per iteration: lanes [0,32) = item 2t,
// lanes [32,64) = item 2t+1. Within a half, lane hl owns dims 8*hl..8*hl+7
// (head0 = hl<16, head1 = hl>=16). Item 0 = self-loop; item i = edge i-1.
// p reduced over 16-lane head groups (xor 8,4,2,1). Inactive slots use
// p = -1e30 (finite: avoids -inf - -inf NaN for deg-0 nodes).
// The two halves' (m,l,acc) merge exactly at the end via shfl_xor 32.

#define NEGBIG -1e30f

template<bool FUSED>
__global__ __launch_bounds__(256) void gat_agg(
    const _Float16* __restrict__ xsh, const float* __restrict__ xd,
    const float* __restrict__ att, const float* __restrict__ bias,
    const int* __restrict__ row_ptr, const int* __restrict__ csr_src,
    __hip_bfloat16* __restrict__ outb, float* __restrict__ outf,
    const float* __restrict__ w34, int n)
{
    int node = blockIdx.x * 4 + (threadIdx.x >> 6);
    if (node >= n) return;
    int lane = threadIdx.x & 63;
    int hl = lane & 31;          // position within half-wave
    int slot = lane >> 5;        // which edge item of the pair
    int d = hl * 8;              // dim base (0..248)

    float xdv[8], atv[8];
    *(float4*)&xdv[0] = *(const float4*)&xd[(size_t)node * 256 + d];
    *(float4*)&xdv[4] = *(const float4*)&xd[(size_t)node * 256 + d + 4];
    *(float4*)&atv[0] = *(const float4*)&att[d];
    *(float4*)&atv[4] = *(const float4*)&att[d + 4];

    float m = -INFINITY, l = 0.f;
    float acc[8] = {};

    int s = row_ptr[node], e = row_ptr[node + 1];
    int deg = e - s;
    int my_src = (lane < deg) ? csr_src[s + lane] : 0;

    int iters = (deg + 2) >> 1;           // ceil((deg+1)/2)
    for (int t = 0; t < iters; ++t) {
        int item = 2 * t + slot;
        bool act = (item <= deg);
        int eidx = item - 1;
        int bsrc = __shfl(my_src, eidx & 63);
        int srcn = node;
        if (act && item > 0)
            srcn = (eidx < 64) ? bsrc : csr_src[s + eidx];

        f16x8 hv = *(const f16x8*)&xsh[(size_t)srcn * 256 + d];
        float xf[8];
#pragma unroll
        for (int j = 0; j < 8; ++j) xf[j] = (float)hv[j];

        float p = 0.f;
#pragma unroll
        for (int j = 0; j < 8; ++j) {
            float v = xf[j] + xdv[j];
            v = fmaxf(v, 0.2f * v);       // leaky_relu
            p = fmaf(v, atv[j], p);
        }
#pragma unroll
        for (int off = 8; off; off >>= 1) p += __shfl_xor(p, off);  // 16-lane head sum
        if (!act) p = NEGBIG;

        float pm = p - m;                 // first iter: +inf -> full path
        if (__all(pm <= 8.f)) {
            float wgt = __expf(pm);
            l += wgt;
#pragma unroll
            for (int j = 0; j < 8; ++j) acc[j] = fmaf(wgt, xf[j], acc[j]);
        } else {
            float mn = fmaxf(m, p);
            float sc = __expf(m - mn);    // exp(-inf)=0 on first iteration
            float wgt = __expf(p - mn);
            l = l * sc + wgt;
#pragma unroll
            for (int j = 0; j < 8; ++j) acc[j] = fmaf(wgt, xf[j], acc[j] * sc);
            m = mn;
        }
    }

    // merge the two halves' online-softmax states (symmetric, exact fp32)
    float mo = __shfl_xor(m, 32);
    float lo = __shfl_xor(l, 32);
    float mt = fmaxf(m, mo);
    float sa = __expf(m - mt);
    float sb = __expf(mo - mt);
    float lt = l * sa + lo * sb;
    float om[8];
#pragma unroll
    for (int j = 0; j < 8; ++j)
        om[j] = acc[j] * sa + __shfl_xor(acc[j], 32) * sb;

    float inv = 1.f / (lt + 1e-16f);
    float bvv[8];
    *(float4*)&bvv[0] = *(const float4*)&bias[d];
    *(float4*)&bvv[4] = *(const float4*)&bias[d + 4];
    float o[8];
#pragma unroll
    for (int j = 0; j < 8; ++j)
        o[j] = fmaxf(fmaf(om[j], inv, bvv[j]), 0.f);

    if (!FUSED) {
        if (lane < 32) {
            uint u[4];
#pragma unroll
            for (int j = 0; j < 4; ++j) {
                __hip_bfloat16 a = __float2bfloat16(o[2 * j]);
                __hip_bfloat16 b = __float2bfloat16(o[2 * j + 1]);
                u[j] = (uint)(*(unsigned short*)&a) | ((uint)(*(unsigned short*)&b) << 16);
            }
            *(uint4*)&outb[(size_t)node * 256 + d] = make_uint4(u[0], u[1], u[2], u[3]);
        }
    } else {
        float wv[8];
        *(float4*)&wv[0] = *(const float4*)&w34[d];
        *(float4*)&wv[4] = *(const float4*)&w34[d + 4];
        float pp = 0.f;
#pragma unroll
        for (int j = 0; j < 8; ++j) pp = fmaf(o[j], wv[j], pp);
#pragma unroll
        for (int off = 16; off; off >>= 1) pp += __shfl_xor(pp, off);  // 32-lane sum
        if (lane == 0) outf[node] = 1.f / (1.f + __expf(-(pp + w34[256])));
    }
}

// ---------------------------------------------------------------------------

extern "C" void kernel_launch(void* const* d_in, const int* in_sizes, int n_in,
                              void* d_out, int out_size, void* d_ws, size_t ws_size,
                              hipStream_t stream)
{
    const float* x     = (const float*)d_in[0];
    const int*   ei    = (const int*)d_in[1];
    const float* Wl1   = (const float*)d_in[2];
    const float* bl1   = (const float*)d_in[3];
    const float* Wr1   = (const float*)d_in[4];
    const float* br1   = (const float*)d_in[5];
    const float* att1  = (const float*)d_in[6];
    const float* bias1 = (const float*)d_in[7];
    const float* Wl2   = (const float*)d_in[8];
    const float* bl2   = (const float*)d_in[9];
    const float* Wr2   = (const float*)d_in[10];
    const float* br2   = (const float*)d_in[11];
    const float* att2  = (const float*)d_in[12];
    const float* bias2 = (const float*)d_in[13];
    const float* W3    = (const float*)d_in[14];
    const float* b3    = (const float*)d_in[15];
    const float* W4    = (const float*)d_in[16];
    const float* b4    = (const float*)d_in[17];

    const int N = in_sizes[0] / 128;     // 50000
    const int E = in_sizes[1] / 2;       // 600000
    const int Mp = ((N + TM - 1) / TM) * TM;   // 50048 padded rows
    const int* src = ei;
    const int* dst = ei + E;

    char* ws = (char*)d_ws;
    _Float16*       xsh     = (_Float16*)(ws + 0);                 // [N][256] fp16
    float*          xd      = (float*)(ws + 25600000);             // [N][256] fp32
    __hip_bfloat16* xbf     = (__hip_bfloat16*)(ws + 76800000);    // [Mp][128] bf16
    __hip_bfloat16* hbf     = (__hip_bfloat16*)(ws + 89612288);    // [Mp][256] bf16
    __hip_bfloat16* Wt1     = (__hip_bfloat16*)(ws + 115236864);   // [512][128] bf16
    __hip_bfloat16* Wt2     = (__hip_bfloat16*)(ws + 115367936);   // [512][256] bf16
    int*            row_ptr = (int*)(ws + 115630080);              // N+1
    int*            counts  = (int*)(ws + 115830144);              // N
    int*            cursor  = (int*)(ws + 116030144);              // N
    int*            csr_src = (int*)(ws + 116230144);              // E
    float*          w34     = (float*)(ws + 118630144);            // 257

    // ---- CSR build + weight prep ----
    hipMemsetAsync(counts, 0, N * sizeof(int), stream);
    count_edges<<<(E + 255) / 256, 256, 0, stream>>>(dst, counts, E);
    scan_kernel<<<1, 1024, 0, stream>>>(counts, row_ptr, cursor, N);
    scatter_edges<<<(E + 255) / 256, 256, 0, stream>>>(src, dst, cursor, csr_src, E);
    w34_kernel<<<65, 256, 0, stream>>>(W3, b3, W4, b4, w34);
    prep_wt<<<(512 * 128 + 255) / 256, 256, 0, stream>>>(Wl1, Wr1, Wt1, 128);
    prep_wt<<<(512 * 256 + 255) / 256, 256, 0, stream>>>(Wl2, Wr2, Wt2, 256);
    conv_bf16<<<(N * 128 / 4 + 255) / 256, 256, 0, stream>>>(x, xbf, N * 128);

    dim3 gemmGrid(512 / TN, Mp / TM);
    int aggBlocks = (N + 3) / 4;

    // ---- layer 1 ----
    gemm_mfma<<<gemmGrid, 256, 0, stream>>>(xbf, Wt1, bl1, br1, xsh, xd, N, 128);
    gat_agg<false><<<aggBlocks, 256, 0, stream>>>(xsh, xd, att1, bias1, row_ptr, csr_src,
                                                  hbf, nullptr, nullptr, N);

    // ---- layer 2 (+ fused post-MLP) ----
    gemm_mfma<<<gemmGrid, 256, 0, stream>>>(hbf, Wt2, bl2, br2, xsh, xd, N, 256);
    gat_agg<true><<<aggBlocks, 256, 0, stream>>>(xsh, xd, att2, bias2, row_ptr, csr_src,
                                                 nullptr, (float*)d_out, w34, N);
}